// Round 1
// 1154.515 us; speedup vs baseline: 1.2133x; 1.2133x over previous
//
#include <hip/hip_runtime.h>
#include <stdint.h>

#define DEVFN __device__ __forceinline__

// Fixed problem shape: x(4,2048,4096) fp32, W(11008,4096) i32,
// snz(32,11008,2) fp32, bias(11008) fp32, GS=128. Out (8192,11008) fp32.
constexpr int M_DIM = 8192;
constexpr int K_DIM = 4096;
constexpr int N_DIM = 11008;
constexpr int GS = 128;
constexpr int NGROUPS = K_DIM / GS;  // 32

typedef __bf16 bf16_t;
typedef bf16_t bf16x8 __attribute__((ext_vector_type(8)));
typedef float f32x4 __attribute__((ext_vector_type(4)));

DEVFN ushort f2bf(float f) {
  uint32_t u = __builtin_bit_cast(uint32_t, f);
  u += 0x7fffu + ((u >> 16) & 1u);   // RNE; inputs are finite
  return (ushort)(u >> 16);
}

// ---------------- x fp32 -> bf16 ----------------
__global__ __launch_bounds__(256) void k_cvt_x(const float* __restrict__ x,
                                               ushort* __restrict__ out) {
  const size_t i4 = (size_t)blockIdx.x * 256 + threadIdx.x;  // quad index, exact grid
  const float4 v = ((const float4*)x)[i4];
  ushort4 r;
  r.x = f2bf(v.x); r.y = f2bf(v.y); r.z = f2bf(v.z); r.w = f2bf(v.w);
  ((ushort4*)out)[i4] = r;
}

// ---------------- W int32 -> bf16 dequant (w*s+z) ----------------
__global__ __launch_bounds__(256) void k_dequant_w(const int* __restrict__ w,
                                                   const float* __restrict__ snz,
                                                   ushort* __restrict__ out) {
  const size_t i4 = (size_t)blockIdx.x * 256 + threadIdx.x;  // quad index, exact grid
  const size_t idx = i4 * 4;
  const int o = (int)(idx >> 12);     // / 4096
  const int i = (int)(idx & 4095);
  const int g = i >> 7;               // / 128 (4 consecutive elems share a group)
  const float2 sz = ((const float2*)snz)[(size_t)g * N_DIM + o];
  const int4 wv = ((const int4*)w)[i4];
  ushort4 r;
  r.x = f2bf((float)wv.x * sz.x + sz.y);
  r.y = f2bf((float)wv.y * sz.x + sz.y);
  r.z = f2bf((float)wv.z * sz.x + sz.y);
  r.w = f2bf((float)wv.w * sz.x + sz.y);
  ((ushort4*)out)[i4] = r;
}

// ================= 256x256 8-phase bf16 GEMM (A: MxK, B: NxK = B^T), +bias =====
//
// Structure per cdna_hip_programming.md §5 "256² 8-phase template" (m194-m201):
//   BM=BN=256, BK=64, 8 waves (2M x 4N), 512 thr, 128 KiB LDS (2 buf x (A+B)).
//   Fixed buffer mapping: even K-tile -> buf0, odd -> buf1 (no runtime cur).
//   LDS swizzle: 16B-chunk XOR with (row&7)  (G4 fix; conflict-free for 128B rows).
//   Staging: global_load_lds w=16, linear LDS dest + inverse-swizzled global src
//   (rule #21: source permutation == read permutation, both involutions).
//
// Per-iteration (2 K-tiles t=2i in buf0, t+1 in buf1), 8 phases:
//   phase: {ds_read frags | stage 1 half-tile | BAR | lgkmcnt(0) | prio1 16xMFMA prio0 | [vmcnt(4)] | BAR}
//   reads:  P1 A0+B01(12) P2 B23(4) P3 A1(8) P4 - | P5..P8 same on buf1
//   quads:  P1 acc[0-3][0-1] P2 [0-3][2-3] P3 [4-7][2-3] P4 [4-7][0-1] | mirror
//   stages: P1 buf1.A0(t+1) P2 buf1.A1(t+1) P3 buf0.B0(t+2) P4 buf0.B1(t+2)
//           P5 buf0.A0(t+2) P6 buf0.A1(t+2) P7 buf1.B0(t+3) P8 buf1.B1(t+3)
//   Safety (stage slot > last LDS-read phase of that region, barrier between):
//     buf0.B last read P2 -> staged P3/P4; buf0.A last read P3 -> P5/P6;
//     buf1.B last read P6 -> P7/P8; buf1.A last read P7 -> next P1/P2.  All OK.
//   vmcnt(4) @P4: leaves P3,P4 stages (buf0.B) in flight; guarantees tile t+1
//   (prev P7/P8 + this P1/P2) landed before P5 reads buf1.   @P8: leaves P7,P8
//   in flight; guarantees tile t+2 (P3..P6) landed before next P1 reads buf0.
//   Never vmcnt(0) in the main loop (T4).
constexpr int BM2 = 256, BN2 = 256, BK2 = 64;
constexpr int NBM2 = M_DIM / BM2;   // 32
constexpr int NBN2 = N_DIM / BN2;   // 43
constexpr int KT2 = K_DIM / BK2;    // 64
constexpr int NWG2 = NBM2 * NBN2;   // 1376 = 8 * 172 (bijective XCD swizzle)

#define BAR() __builtin_amdgcn_s_barrier()
#define LGKM0() asm volatile("s_waitcnt lgkmcnt(0)" ::: "memory")
#define VMC4() asm volatile("s_waitcnt vmcnt(4)" ::: "memory")
#define VMC0() asm volatile("s_waitcnt vmcnt(0)" ::: "memory")

DEVFN void gld16(const ushort* g, ushort* l) {
  __builtin_amdgcn_global_load_lds(
      (const __attribute__((address_space(1))) void*)g,
      (__attribute__((address_space(3))) void*)l, 16, 0, 0);
}

// Stage one 128-row x 64-col half-tile: 2 x global_load_lds per thread.
// Thread tid covers rows {srow, srow+64} of the half; LDS dest is linear
// (wave-uniform base + lane*16), global source column pre-XOR-swizzled.
DEVFN void stage_half(const ushort* gbase, int h, int kt, ushort* lp) {
  const ushort* s = gbase + (size_t)(h * 128) * K_DIM + kt * 64;
  gld16(s, lp);
  gld16(s + (size_t)64 * K_DIM, lp + 4096);
}

template <int H>
DEVFN void lda(const ushort* p0, const ushort* p1, bf16x8 (&af)[4][2]) {
#pragma unroll
  for (int mi = 0; mi < 4; ++mi) {
    af[mi][0] = *(const bf16x8*)(p0 + (H * 4 + mi) * 1024);
    af[mi][1] = *(const bf16x8*)(p1 + (H * 4 + mi) * 1024);
  }
}
template <int P>
DEVFN void ldb(const ushort* p0, const ushort* p1, bf16x8 (&bv)[4][2]) {
#pragma unroll
  for (int q = 0; q < 2; ++q) {
    bv[P * 2 + q][0] = *(const bf16x8*)(p0 + (P * 2 + q) * 1024);
    bv[P * 2 + q][1] = *(const bf16x8*)(p1 + (P * 2 + q) * 1024);
  }
}
template <int H, int P>
DEVFN void mm16(f32x4 (&acc)[8][4], const bf16x8 (&af)[4][2], const bf16x8 (&bv)[4][2]) {
#pragma unroll
  for (int kk = 0; kk < 2; ++kk)
#pragma unroll
    for (int mi = 0; mi < 4; ++mi)
#pragma unroll
      for (int ni = 0; ni < 2; ++ni)
        acc[H * 4 + mi][P * 2 + ni] = __builtin_amdgcn_mfma_f32_16x16x32_bf16(
            af[mi][kk], bv[P * 2 + ni][kk], acc[H * 4 + mi][P * 2 + ni], 0, 0, 0);
}

__global__ __launch_bounds__(512) void k_gemm256(const ushort* __restrict__ A,
                                                 const ushort* __restrict__ B,
                                                 const float* __restrict__ bias,
                                                 float* __restrict__ C) {
  // 128 KiB: [A buf0 | B buf0 | A buf1 | B buf1], each 256x64 bf16 = 32 KB.
  // gfx950 LDS = 160 KiB/CU; 1 block/CU by design (HK/m201 occupancy model).
  __shared__ __align__(16) ushort smem[65536];

  const int tid = threadIdx.x;
  const int wave = tid >> 6;
  const int lane = tid & 63;
  const int wm = wave >> 2;   // 0..1  (M half)
  const int wn = wave & 3;    // 0..3  (N quarter)
  const int fr = lane & 15;
  const int quad = lane >> 4;
  const int frq = fr & 7;

  // Bijective XCD swizzle (T1): 1376 % 8 == 0, bm-major inside each XCD.
  const int bid = blockIdx.x;
  const int wg = (bid & 7) * (NWG2 / 8) + (bid >> 3);
  const int bm = wg / NBN2;
  const int bn = wg - bm * NBN2;

  // ds_read bases (ushort units). Fragment (mi|ni, kk): logical 16B chunk
  // (kk*4+quad) XOR-swizzled with row&7 == fr&7. kk=1 base is separate
  // pointer (XOR with 64B is not additive).
  const int ch0 = ((quad ^ frq) << 3);
  const int ch1 = (((4 | quad) ^ frq) << 3);
  const ushort* pA00 = smem + (wm * 128 + fr) * 64 + ch0;
  const ushort* pA01 = smem + (wm * 128 + fr) * 64 + ch1;
  const ushort* pA10 = pA00 + 32768;
  const ushort* pA11 = pA01 + 32768;
  const ushort* pB00 = smem + 16384 + (wn * 64 + fr) * 64 + ch0;
  const ushort* pB01 = smem + 16384 + (wn * 64 + fr) * 64 + ch1;
  const ushort* pB10 = pB00 + 32768;
  const ushort* pB11 = pB01 + 32768;

  // Stage source: linear LDS slot (j*512+tid)*16B => row j*64 + tid/8,
  // chunk tid&7. Inverse swizzle: fetch global chunk (tid&7)^(row&7).
  const int srow = tid >> 3;                            // 0..63
  const int scol = ((tid & 7) ^ (srow & 7)) * 8;        // elems
  const ushort* pAg = A + (size_t)(bm * 256 + srow) * K_DIM + scol;
  const ushort* pBg = B + (size_t)(bn * 256 + srow) * K_DIM + scol;
  ushort* const ws = smem + wave * 512;  // this wave's 1KB slice per issue

  f32x4 acc[8][4] = {};

  // Prologue: tile0 -> buf0 (8 loads), tile1 B-halves -> buf1 (4 loads).
  // vmcnt(4): tile0 landed, tile1.B may still fly. Tile1.A staged at P1/P2.
  stage_half(pAg, 0, 0, ws + 0);
  stage_half(pAg, 1, 0, ws + 8192);
  stage_half(pBg, 0, 0, ws + 16384);
  stage_half(pBg, 1, 0, ws + 24576);
  stage_half(pBg, 0, 1, ws + 49152);
  stage_half(pBg, 1, 1, ws + 57344);
  VMC4();
  BAR();

#pragma unroll 1
  for (int it = 0; it < KT2 / 2; ++it) {
    const int t1 = 2 * it + 1;
    const int t2 = (2 * it + 2 < KT2) ? 2 * it + 2 : KT2 - 1;  // clamped: last
    const int t3 = (2 * it + 3 < KT2) ? 2 * it + 3 : KT2 - 1;  // iter stages are
    bf16x8 af[4][2], bv[4][2];                                  // dead but safe
    // ---- P1: read buf0 A-half0 + B ni0-1; stage buf1.A0(t1)
    lda<0>(pA00, pA01, af);
    ldb<0>(pB00, pB01, bv);
    stage_half(pAg, 0, t1, ws + 32768);
    BAR(); LGKM0();
    __builtin_amdgcn_s_setprio(1); mm16<0, 0>(acc, af, bv); __builtin_amdgcn_s_setprio(0);
    BAR();
    // ---- P2: read B ni2-3; stage buf1.A1(t1)
    ldb<1>(pB00, pB01, bv);
    stage_half(pAg, 1, t1, ws + 40960);
    BAR(); LGKM0();
    __builtin_amdgcn_s_setprio(1); mm16<0, 1>(acc, af, bv); __builtin_amdgcn_s_setprio(0);
    BAR();
    // ---- P3: read A-half1; stage buf0.B0(t2)
    lda<1>(pA00, pA01, af);
    stage_half(pBg, 0, t2, ws + 16384);
    BAR(); LGKM0();
    __builtin_amdgcn_s_setprio(1); mm16<1, 1>(acc, af, bv); __builtin_amdgcn_s_setprio(0);
    BAR();
    // ---- P4: stage buf0.B1(t2); counted vmcnt -> buf1 tile t1 fully landed
    stage_half(pBg, 1, t2, ws + 24576);
    BAR();
    __builtin_amdgcn_s_setprio(1); mm16<1, 0>(acc, af, bv); __builtin_amdgcn_s_setprio(0);
    VMC4();
    BAR();
    // ---- P5: buf1 A-half0 + B ni0-1; stage buf0.A0(t2)
    lda<0>(pA10, pA11, af);
    ldb<0>(pB10, pB11, bv);
    stage_half(pAg, 0, t2, ws + 0);
    BAR(); LGKM0();
    __builtin_amdgcn_s_setprio(1); mm16<0, 0>(acc, af, bv); __builtin_amdgcn_s_setprio(0);
    BAR();
    // ---- P6: buf1 B ni2-3; stage buf0.A1(t2)
    ldb<1>(pB10, pB11, bv);
    stage_half(pAg, 1, t2, ws + 8192);
    BAR(); LGKM0();
    __builtin_amdgcn_s_setprio(1); mm16<0, 1>(acc, af, bv); __builtin_amdgcn_s_setprio(0);
    BAR();
    // ---- P7: buf1 A-half1; stage buf1.B0(t3)
    lda<1>(pA10, pA11, af);
    stage_half(pBg, 0, t3, ws + 49152);
    BAR(); LGKM0();
    __builtin_amdgcn_s_setprio(1); mm16<1, 1>(acc, af, bv); __builtin_amdgcn_s_setprio(0);
    BAR();
    // ---- P8: stage buf1.B1(t3); counted vmcnt -> buf0 tile t2 fully landed
    stage_half(pBg, 1, t3, ws + 57344);
    BAR();
    __builtin_amdgcn_s_setprio(1); mm16<1, 0>(acc, af, bv); __builtin_amdgcn_s_setprio(0);
    VMC4();
    BAR();
  }
  VMC0();  // drain trailing stages before endpgm/epilogue

  // Epilogue. C/D layout (m89/m91, same convention as verified 128² kernel):
  // col = lane&15, row = quad*4 + reg.
  const int row0 = bm * 256 + wm * 128 + quad * 4;
  const int col0 = bn * 256 + wn * 64 + fr;
#pragma unroll
  for (int ni = 0; ni < 4; ++ni) {
    const int col = col0 + ni * 16;
    const float bvv = bias[col];
#pragma unroll
    for (int mi = 0; mi < 8; ++mi) {
      float* cp = C + (size_t)(row0 + mi * 16) * N_DIM + col;
#pragma unroll
      for (int r = 0; r < 4; ++r)
        cp[(size_t)r * N_DIM] = acc[mi][ni][r] + bvv;
    }
  }
}

// ---------------- fallback (ws too small): naive but correct ----------------
__global__ __launch_bounds__(256) void k_naive(const float* __restrict__ x,
                                               const int* __restrict__ w,
                                               const float* __restrict__ snz,
                                               const float* __restrict__ bias,
                                               float* __restrict__ y) {
  const int o = blockIdx.x * 256 + threadIdx.x;  // 11008 = 43*256 exact
  const int m = blockIdx.y;
  const float* xr = x + (size_t)m * K_DIM;
  const int* wr = w + (size_t)o * K_DIM;
  float acc = 0.f;
  for (int g = 0; g < NGROUPS; ++g) {
    const float2 sz = ((const float2*)snz)[(size_t)g * N_DIM + o];
    float pd = 0.f, px = 0.f;
    const int base = g * GS;
    for (int i = 0; i < GS; i += 4) {
      float4 xv = *(const float4*)(xr + base + i);
      int4 wv = *(const int4*)(wr + base + i);
      pd += xv.x * wv.x + xv.y * wv.y + xv.z * wv.z + xv.w * wv.w;
      px += xv.x + xv.y + xv.z + xv.w;
    }
    acc += sz.x * pd + sz.y * px;
  }
  y[(size_t)m * N_DIM + o] = acc + bias[o];
}

extern "C" void kernel_launch(void* const* d_in, const int* in_sizes, int n_in,
                              void* d_out, int out_size, void* d_ws, size_t ws_size,
                              hipStream_t stream) {
  const float* x    = (const float*)d_in[0];
  const int*   w    = (const int*)d_in[1];
  const float* snz  = (const float*)d_in[2];
  const float* bias = (const float*)d_in[3];
  float* out = (float*)d_out;

  const size_t wbytes = (size_t)N_DIM * K_DIM * 2;  // 90,177,536
  const size_t xbytes = (size_t)M_DIM * K_DIM * 2;  // 67,108,864

  if (ws_size >= wbytes + xbytes) {
    ushort* wbf = (ushort*)d_ws;
    ushort* xbf = (ushort*)((char*)d_ws + wbytes);
    // x: 8192*4096/4 quads = 8,388,608 -> 32768 blocks exact
    k_cvt_x<<<dim3(32768), dim3(256), 0, stream>>>(x, xbf);
    // W: 11008*4096/4 quads = 11,272,192 -> 44032 blocks exact
    k_dequant_w<<<dim3(44032), dim3(256), 0, stream>>>(w, snz, wbf);
    // GEMM: 32 * 43 = 1376 blocks, 512 threads (8 waves)
    k_gemm256<<<dim3(NWG2), dim3(512), 0, stream>>>(xbf, wbf, bias, out);
  } else {
    k_naive<<<dim3(N_DIM / 256, M_DIM), dim3(256), 0, stream>>>(x, w, snz, bias, out);
  }
}

// Round 3
// 1138.270 us; speedup vs baseline: 1.2306x; 1.0143x over previous
//
#include <hip/hip_runtime.h>
#include <stdint.h>

#define DEVFN __device__ __forceinline__

// Fixed problem shape: x(4,2048,4096) fp32, W(11008,4096) i32,
// snz(32,11008,2) fp32, bias(11008) fp32, GS=128. Out (8192,11008) fp32.
constexpr int M_DIM = 8192;
constexpr int K_DIM = 4096;
constexpr int N_DIM = 11008;
constexpr int GS = 128;
constexpr int NGROUPS = K_DIM / GS;  // 32

typedef __bf16 bf16_t;
typedef bf16_t bf16x8 __attribute__((ext_vector_type(8)));
typedef float f32x4 __attribute__((ext_vector_type(4)));

DEVFN ushort f2bf(float f) {
  uint32_t u = __builtin_bit_cast(uint32_t, f);
  u += 0x7fffu + ((u >> 16) & 1u);   // RNE; inputs are finite
  return (ushort)(u >> 16);
}

// ---------------- x fp32 -> bf16 ----------------
__global__ __launch_bounds__(256) void k_cvt_x(const float* __restrict__ x,
                                               ushort* __restrict__ out) {
  const size_t i4 = (size_t)blockIdx.x * 256 + threadIdx.x;  // quad index, exact grid
  const float4 v = ((const float4*)x)[i4];
  ushort4 r;
  r.x = f2bf(v.x); r.y = f2bf(v.y); r.z = f2bf(v.z); r.w = f2bf(v.w);
  ((ushort4*)out)[i4] = r;
}

// ---------------- W int32 -> bf16 dequant (w*s+z) ----------------
__global__ __launch_bounds__(256) void k_dequant_w(const int* __restrict__ w,
                                                   const float* __restrict__ snz,
                                                   ushort* __restrict__ out) {
  const size_t i4 = (size_t)blockIdx.x * 256 + threadIdx.x;  // quad index, exact grid
  const size_t idx = i4 * 4;
  const int o = (int)(idx >> 12);     // / 4096
  const int i = (int)(idx & 4095);
  const int g = i >> 7;               // / 128 (4 consecutive elems share a group)
  const float2 sz = ((const float2*)snz)[(size_t)g * N_DIM + o];
  const int4 wv = ((const int4*)w)[i4];
  ushort4 r;
  r.x = f2bf((float)wv.x * sz.x + sz.y);
  r.y = f2bf((float)wv.y * sz.x + sz.y);
  r.z = f2bf((float)wv.z * sz.x + sz.y);
  r.w = f2bf((float)wv.w * sz.x + sz.y);
  ((ushort4*)out)[i4] = r;
}

// ================= 256x256 8-phase bf16 GEMM (A: MxK, B: NxK = B^T), +bias =====
//
// v3: race-fixed software-pipelined ds_reads.
// v2 BUG: vmcnt is PER-WAVE; tail reads of a newly staged buffer after VMC4
// but BEFORE the barrier could see other waves' stages still in flight.
// PROTOCOL (v3): every read of newly staged data is preceded (in program
// order, all waves) by {per-wave VMC validating that buffer; s_barrier}.
// Achieved by validating one phase early: VMC2 at end of P3/P7.
//
// Geometry: BM=BN=256, BK=64, 8 waves (2M x 4N), 512 thr, 128 KiB LDS.
// Buffers: even K-tile -> buf0, odd -> buf1 (compile-time mapping).
// Swizzle: 16B-chunk XOR (row&7); linear LDS dest + inverse-swizzled global
// source (rule #21). Round-1 measured 0 bank conflicts with this scheme.
//
// Phase p: stage(p); prio1 MFMA(p) prio0; [VMC2 @P3/P7]; tail-reads; BARM
//   MFMA quadrants: P1<0,0> P2<0,1> P3<1,1> P4<1,0> on buf0, P5..P8 mirror on
//   buf1 (same acc order as round 1 -> bit-identical output).
//   stages: P1 b1.A0(t1) P2 b1.A1(t1) P3 b0.B0(t2) P4 b0.B1(t2)
//           P5 b0.A0(t2) P6 b0.A1(t2) P7 b1.B0(t3) P8 b1.B1(t3)
//   tail-reads (into af/bv regs, consumed by next phase's MFMA):
//           P1: b0.B23  P2: b0.A1  P3: -  P4: b1.A0 + b1.B01
//           P5: b1.B23  P6: b1.A1  P7: -  P8: b0.A0 + b0.B01
//
// Safety proofs:
//  * vmcnt(2) at end P3 (2 loads/phase): outstanding = prev-P7,P8 + P1,P2,P3
//    = 10 -> retires oldest 8 = b1.B0,B1(t1) + b1.A0,A1(t1) => buf1 t1 fully
//    landed (this wave). BARM end-P3 => ALL waves validated => tail-P4 reads
//    of buf1 are safe. Mirror at P7 for buf0 t2 (P3..P6 retired).
//    Iter 0: prologue VMC4 retired b0's 8; queue = b1.B(4)+P1(2)+P2(2)+P3(2)
//    = 10, same retirement. Prologue VMC4+BARM validates b0 t0 for its reads.
//  * Tail-read region vs next phase's stage (in flight across one barrier):
//    P1 b0.B23 / P2-stage b1.A1; P2 b0.A1 / P3-stage b0.B0; P4 b1.* /
//    P5-stage b0.A0; P5 b1.B23 / P6-stage b0.A1; P6 b1.A1 / P7-stage b1.B0;
//    P8 b0.* / next-P1-stage b1.A0.  All disjoint.
//  * Stage(p) WAR vs older reads of same region: every region's last LDS read
//    completes >= 2 barriers before its re-stage (reads complete before their
//    consuming MFMA via register dep; checked per region).
//  * Compiler motion: BARM = asm volatile s_barrier with "memory" clobber ->
//    LDS loads cannot hoist above the validating barrier (plain s_barrier
//    intrinsic does not model memory!). VMC asm also clobbers memory.
constexpr int BM2 = 256, BN2 = 256, BK2 = 64;
constexpr int NBM2 = M_DIM / BM2;   // 32
constexpr int NBN2 = N_DIM / BN2;   // 43
constexpr int KT2 = K_DIM / BK2;    // 64
constexpr int NWG2 = NBM2 * NBN2;   // 1376 = 8 * 172 (bijective XCD swizzle)

#define BARM() asm volatile("s_barrier" ::: "memory")
#define VMC2() asm volatile("s_waitcnt vmcnt(2)" ::: "memory")
#define VMC4() asm volatile("s_waitcnt vmcnt(4)" ::: "memory")
#define VMC0() asm volatile("s_waitcnt vmcnt(0)" ::: "memory")
#define PRIO1() __builtin_amdgcn_s_setprio(1)
#define PRIO0() __builtin_amdgcn_s_setprio(0)

DEVFN void gld16(const ushort* g, ushort* l) {
  __builtin_amdgcn_global_load_lds(
      (const __attribute__((address_space(1))) void*)g,
      (__attribute__((address_space(3))) void*)l, 16, 0, 0);
}

// Stage one 128-row x 64-col half-tile: 2 x global_load_lds per thread.
DEVFN void stage_half(const ushort* gbase, int h, int kt, ushort* lp) {
  const ushort* s = gbase + (size_t)(h * 128) * K_DIM + kt * 64;
  gld16(s, lp);
  gld16(s + (size_t)64 * K_DIM, lp + 4096);
}

template <int H>
DEVFN void lda(const ushort* p0, const ushort* p1, bf16x8 (&af)[4][2]) {
#pragma unroll
  for (int mi = 0; mi < 4; ++mi) {
    af[mi][0] = *(const bf16x8*)(p0 + (H * 4 + mi) * 1024);
    af[mi][1] = *(const bf16x8*)(p1 + (H * 4 + mi) * 1024);
  }
}
template <int P>
DEVFN void ldb(const ushort* p0, const ushort* p1, bf16x8 (&bv)[4][2]) {
#pragma unroll
  for (int q = 0; q < 2; ++q) {
    bv[P * 2 + q][0] = *(const bf16x8*)(p0 + (P * 2 + q) * 1024);
    bv[P * 2 + q][1] = *(const bf16x8*)(p1 + (P * 2 + q) * 1024);
  }
}
template <int H, int P>
DEVFN void mm16(f32x4 (&acc)[8][4], const bf16x8 (&af)[4][2], const bf16x8 (&bv)[4][2]) {
#pragma unroll
  for (int kk = 0; kk < 2; ++kk)
#pragma unroll
    for (int mi = 0; mi < 4; ++mi)
#pragma unroll
      for (int ni = 0; ni < 2; ++ni)
        acc[H * 4 + mi][P * 2 + ni] = __builtin_amdgcn_mfma_f32_16x16x32_bf16(
            af[mi][kk], bv[P * 2 + ni][kk], acc[H * 4 + mi][P * 2 + ni], 0, 0, 0);
}

__global__ __launch_bounds__(512, 2) void k_gemm256(const ushort* __restrict__ A,
                                                    const ushort* __restrict__ B,
                                                    const float* __restrict__ bias,
                                                    float* __restrict__ C) {
  // 128 KiB: [A buf0 | B buf0 | A buf1 | B buf1], each 256x64 bf16 = 32 KB.
  __shared__ __align__(16) ushort smem[65536];

  const int tid = threadIdx.x;
  const int wave = tid >> 6;
  const int lane = tid & 63;
  const int wm = wave >> 2;   // 0..1  (M half)
  const int wn = wave & 3;    // 0..3  (N quarter)
  const int fr = lane & 15;
  const int quad = lane >> 4;
  const int frq = fr & 7;

  // Bijective XCD swizzle (T1): 1376 % 8 == 0, bm-major inside each XCD.
  const int bid = blockIdx.x;
  const int wg = (bid & 7) * (NWG2 / 8) + (bid >> 3);
  const int bm = wg / NBN2;
  const int bn = wg - bm * NBN2;

  // ds_read bases (ushort units). Fragment (mi|ni, kk): logical 16B chunk
  // (kk*4+quad) XOR-swizzled with row&7 == fr&7.
  const int ch0 = ((quad ^ frq) << 3);
  const int ch1 = (((4 | quad) ^ frq) << 3);
  const ushort* pA00 = smem + (wm * 128 + fr) * 64 + ch0;
  const ushort* pA01 = smem + (wm * 128 + fr) * 64 + ch1;
  const ushort* pA10 = pA00 + 32768;
  const ushort* pA11 = pA01 + 32768;
  const ushort* pB00 = smem + 16384 + (wn * 64 + fr) * 64 + ch0;
  const ushort* pB01 = smem + 16384 + (wn * 64 + fr) * 64 + ch1;
  const ushort* pB10 = pB00 + 32768;
  const ushort* pB11 = pB01 + 32768;

  // Stage source: linear LDS slot (j*512+tid)*16B => row j*64 + tid/8,
  // chunk tid&7. Inverse swizzle: fetch global chunk (tid&7)^(row&7).
  const int srow = tid >> 3;                            // 0..63
  const int scol = ((tid & 7) ^ (srow & 7)) * 8;        // elems
  const ushort* pAg = A + (size_t)(bm * 256 + srow) * K_DIM + scol;
  const ushort* pBg = B + (size_t)(bn * 256 + srow) * K_DIM + scol;
  ushort* const ws = smem + wave * 512;  // this wave's 1KB slice per issue

  f32x4 acc[8][4] = {};
  bf16x8 af[4][2], bv[4][2];

  // Prologue: tile0 -> buf0 (8 loads), tile1 B-halves -> buf1 (4 loads).
  // VMC4 retires buf0's 8 loads; BARM makes that all-wave; THEN read buf0
  // fragments for P1 (validate-BAR-read protocol).
  stage_half(pAg, 0, 0, ws + 0);
  stage_half(pAg, 1, 0, ws + 8192);
  stage_half(pBg, 0, 0, ws + 16384);
  stage_half(pBg, 1, 0, ws + 24576);
  stage_half(pBg, 0, 1, ws + 49152);
  stage_half(pBg, 1, 1, ws + 57344);
  VMC4();
  BARM();
  lda<0>(pA00, pA01, af);
  ldb<0>(pB00, pB01, bv);

#pragma unroll 1
  for (int it = 0; it < KT2 / 2; ++it) {
    const int t1 = 2 * it + 1;
    const int t2 = (2 * it + 2 < KT2) ? 2 * it + 2 : KT2 - 1;  // clamped: last
    const int t3 = (2 * it + 3 < KT2) ? 2 * it + 3 : KT2 - 1;  // iter stages dead
    // ---- P1: MFMA (b0.A0 x b0.B01); stage b1.A0(t1); tail-read b0.B23
    stage_half(pAg, 0, t1, ws + 32768);
    PRIO1(); mm16<0, 0>(acc, af, bv); PRIO0();
    ldb<1>(pB00, pB01, bv);
    BARM();
    // ---- P2: MFMA (b0.A0 x b0.B23); stage b1.A1(t1); tail-read b0.A1
    stage_half(pAg, 1, t1, ws + 40960);
    PRIO1(); mm16<0, 1>(acc, af, bv); PRIO0();
    lda<1>(pA00, pA01, af);
    BARM();
    // ---- P3: MFMA (b0.A1 x b0.B23); stage b0.B0(t2); VMC2 retires
    //      prev-P7,P8 + P1,P2 = buf1 tile t1 complete (this wave); BARM
    //      promotes to all-wave. No reads here.
    stage_half(pBg, 0, t2, ws + 16384);
    PRIO1(); mm16<1, 1>(acc, af, bv); PRIO0();
    VMC2();
    BARM();
    // ---- P4: MFMA (b0.A1 x b0.B01); stage b0.B1(t2); tail-read buf1
    //      (validated at end-P3 by ALL waves; disjoint from P5's stage)
    stage_half(pBg, 1, t2, ws + 24576);
    PRIO1(); mm16<1, 0>(acc, af, bv); PRIO0();
    lda<0>(pA10, pA11, af);
    ldb<0>(pB10, pB11, bv);
    BARM();
    // ---- P5: MFMA (b1.A0 x b1.B01); stage b0.A0(t2); tail-read b1.B23
    stage_half(pAg, 0, t2, ws + 0);
    PRIO1(); mm16<0, 0>(acc, af, bv); PRIO0();
    ldb<1>(pB10, pB11, bv);
    BARM();
    // ---- P6: MFMA (b1.A0 x b1.B23); stage b0.A1(t2); tail-read b1.A1
    stage_half(pAg, 1, t2, ws + 8192);
    PRIO1(); mm16<0, 1>(acc, af, bv); PRIO0();
    lda<1>(pA10, pA11, af);
    BARM();
    // ---- P7: MFMA (b1.A1 x b1.B23); stage b1.B0(t3); VMC2 retires
    //      P3..P6 = buf0 tile t2 complete; BARM -> all-wave.
    stage_half(pBg, 0, t3, ws + 49152);
    PRIO1(); mm16<1, 1>(acc, af, bv); PRIO0();
    VMC2();
    BARM();
    // ---- P8: MFMA (b1.A1 x b1.B01); stage b1.B1(t3); tail-read buf0 t2
    //      (validated end-P7; disjoint from next-P1's stage b1.A0)
    stage_half(pBg, 1, t3, ws + 57344);
    PRIO1(); mm16<1, 0>(acc, af, bv); PRIO0();
    lda<0>(pA00, pA01, af);
    ldb<0>(pB00, pB01, bv);
    BARM();
  }
  VMC0();  // drain trailing (dead) stages before epilogue/endpgm

  // Epilogue. C/D layout: col = lane&15, row = quad*4 + reg.
  const int row0 = bm * 256 + wm * 128 + quad * 4;
  const int col0 = bn * 256 + wn * 64 + fr;
#pragma unroll
  for (int ni = 0; ni < 4; ++ni) {
    const int col = col0 + ni * 16;
    const float bvv = bias[col];
#pragma unroll
    for (int mi = 0; mi < 8; ++mi) {
      float* cp = C + (size_t)(row0 + mi * 16) * N_DIM + col;
#pragma unroll
      for (int r = 0; r < 4; ++r)
        cp[(size_t)r * N_DIM] = acc[mi][ni][r] + bvv;
    }
  }
}

// ---------------- fallback (ws too small): naive but correct ----------------
__global__ __launch_bounds__(256) void k_naive(const float* __restrict__ x,
                                               const int* __restrict__ w,
                                               const float* __restrict__ snz,
                                               const float* __restrict__ bias,
                                               float* __restrict__ y) {
  const int o = blockIdx.x * 256 + threadIdx.x;  // 11008 = 43*256 exact
  const int m = blockIdx.y;
  const float* xr = x + (size_t)m * K_DIM;
  const int* wr = w + (size_t)o * K_DIM;
  float acc = 0.f;
  for (int g = 0; g < NGROUPS; ++g) {
    const float2 sz = ((const float2*)snz)[(size_t)g * N_DIM + o];
    float pd = 0.f, px = 0.f;
    const int base = g * GS;
    for (int i = 0; i < GS; i += 4) {
      float4 xv = *(const float4*)(xr + base + i);
      int4 wv = *(const int4*)(wr + base + i);
      pd += xv.x * wv.x + xv.y * wv.y + xv.z * wv.z + xv.w * wv.w;
      px += xv.x + xv.y + xv.z + xv.w;
    }
    acc += sz.x * pd + sz.y * px;
  }
  y[(size_t)m * N_DIM + o] = acc + bias[o];
}

extern "C" void kernel_launch(void* const* d_in, const int* in_sizes, int n_in,
                              void* d_out, int out_size, void* d_ws, size_t ws_size,
                              hipStream_t stream) {
  const float* x    = (const float*)d_in[0];
  const int*   w    = (const int*)d_in[1];
  const float* snz  = (const float*)d_in[2];
  const float* bias = (const float*)d_in[3];
  float* out = (float*)d_out;

  const size_t wbytes = (size_t)N_DIM * K_DIM * 2;  // 90,177,536
  const size_t xbytes = (size_t)M_DIM * K_DIM * 2;  // 67,108,864

  if (ws_size >= wbytes + xbytes) {
    ushort* wbf = (ushort*)d_ws;
    ushort* xbf = (ushort*)((char*)d_ws + wbytes);
    // x: 8192*4096/4 quads = 8,388,608 -> 32768 blocks exact
    k_cvt_x<<<dim3(32768), dim3(256), 0, stream>>>(x, xbf);
    // W: 11008*4096/4 quads = 11,272,192 -> 44032 blocks exact
    k_dequant_w<<<dim3(44032), dim3(256), 0, stream>>>(w, snz, wbf);
    // GEMM: 32 * 43 = 1376 blocks, 512 threads (8 waves)
    k_gemm256<<<dim3(NWG2), dim3(512), 0, stream>>>(xbf, wbf, bias, out);
  } else {
    k_naive<<<dim3(N_DIM / 256, M_DIM), dim3(256), 0, stream>>>(x, w, snz, bias, out);
  }
}